// Round 7
// baseline (333.277 us; speedup 1.0000x reference)
//
#include <hip/hip_runtime.h>
#include <hip/hip_bf16.h>

typedef unsigned short u16;
typedef unsigned int u32;
typedef short bf16x8 __attribute__((ext_vector_type(8)));
typedef float f32x4 __attribute__((ext_vector_type(4)));

#define NTOK 8192
#define HID 768
#define INTER 2048
#define NEXP 8

#define MFMA16(a, b, c) __builtin_amdgcn_mfma_f32_16x16x32_bf16(a, b, c, 0, 0, 0)
#define S_BARRIER() __builtin_amdgcn_s_barrier()
#define SETPRIO(x) __builtin_amdgcn_s_setprio(x)
#define WAITVM(n) asm volatile("s_waitcnt vmcnt(" #n ")" ::: "memory")

__device__ __forceinline__ u16 f2bf(float f) {
    u32 u = __builtin_bit_cast(u32, f);
    u32 r = (u + 0x7FFFu + ((u >> 16) & 1u)) >> 16;
    return (u16)r;
}

__device__ __forceinline__ void gld16(const void* g, void* l) {
    __builtin_amdgcn_global_load_lds((const __attribute__((address_space(1))) void*)g,
                                     (__attribute__((address_space(3))) void*)l, 16, 0, 0);
}

// ---------------- zero out ----------------
__global__ __launch_bounds__(256) void zero_kernel(float4* out4, int n4) {
    int i = blockIdx.x * blockDim.x + threadIdx.x;
    float4 z = {0.f, 0.f, 0.f, 0.f};
    int stride = gridDim.x * blockDim.x;
    for (int k = i; k < n4; k += stride) out4[k] = z;
}

// ---------------- fp32 -> bf16 convert ----------------
__global__ __launch_bounds__(256) void cvt_kernel(const float* __restrict__ src, u16* __restrict__ dst, int n8) {
    int i = blockIdx.x * blockDim.x + threadIdx.x;
    int stride = gridDim.x * blockDim.x;
    for (; i < n8; i += stride) {
        const float4* s = (const float4*)(src + (size_t)i * 8);
        float4 a = s[0], b = s[1];
        u16 r[8] = {f2bf(a.x), f2bf(a.y), f2bf(a.z), f2bf(a.w),
                    f2bf(b.x), f2bf(b.y), f2bf(b.z), f2bf(b.w)};
        *(uint4*)(dst + (size_t)i * 8) = *(const uint4*)r;
    }
}

// ---------------- router: logits, top-2, softmax (NO atomics) ----------------
__global__ __launch_bounds__(256) void router2(const float* __restrict__ x, const float* __restrict__ rw,
                                               u32* __restrict__ route, float* __restrict__ wslot) {
    int wv = threadIdx.x >> 6, ln = threadIdx.x & 63;
    int t = blockIdx.x * 4 + wv;
    if (t >= NTOK) return;
    float xr[12];
#pragma unroll
    for (int j = 0; j < 12; j++) xr[j] = x[(size_t)t * HID + ln + j * 64];
    float lg[NEXP];
#pragma unroll
    for (int e = 0; e < NEXP; e++) {
        float a = 0.f;
#pragma unroll
        for (int j = 0; j < 12; j++) a += xr[j] * rw[e * HID + ln + j * 64];
#pragma unroll
        for (int off = 32; off; off >>= 1) a += __shfl_xor(a, off);
        lg[e] = a;
    }
    int i0 = 0;
    float v0 = lg[0];
#pragma unroll
    for (int e = 1; e < NEXP; e++)
        if (lg[e] > v0) { v0 = lg[e]; i0 = e; }
    int i1 = -1;
    float v1 = -1e30f;
#pragma unroll
    for (int e = 0; e < NEXP; e++) {
        if (e == i0) continue;
        if (lg[e] > v1) { v1 = lg[e]; i1 = e; }
    }
    float w0 = 1.f / (1.f + __expf(v1 - v0));
    float w1 = 1.f - w0;
    if (ln == 0) {
        wslot[0 * NTOK + t] = w0;
        wslot[1 * NTOK + t] = w1;
        route[t] = (u32)i0 | ((u32)i1 << 8);
    }
}

// ---------------- scatter: deterministic counting sort + fused schedule ----------------
__global__ __launch_bounds__(1024) void scatter_kernel(const u32* __restrict__ route, int* __restrict__ counts,
                                                       int* __restrict__ tokslot, int* __restrict__ ntiles,
                                                       int* __restrict__ tiledesc) {
    __shared__ int sc[NEXP][1024];
    int tid = threadIdx.x;
    u32 rt[8];
    int cnt[NEXP] = {0, 0, 0, 0, 0, 0, 0, 0};
#pragma unroll
    for (int k = 0; k < 8; k++) {
        rt[k] = route[tid * 8 + k];
        cnt[rt[k] & 255]++;
        cnt[(rt[k] >> 8) & 255]++;
    }
#pragma unroll
    for (int e = 0; e < NEXP; e++) sc[e][tid] = cnt[e];
    __syncthreads();
    for (int off = 1; off < 1024; off <<= 1) {
        int v[NEXP];
#pragma unroll
        for (int e = 0; e < NEXP; e++) v[e] = (tid >= off) ? sc[e][tid - off] : 0;
        __syncthreads();
#pragma unroll
        for (int e = 0; e < NEXP; e++)
            if (tid >= off) sc[e][tid] += v[e];
        __syncthreads();
    }
    int base[NEXP];
#pragma unroll
    for (int e = 0; e < NEXP; e++) base[e] = sc[e][tid] - cnt[e];
#pragma unroll
    for (int k = 0; k < 8; k++) {
        int t = tid * 8 + k;
        int e0 = rt[k] & 255, e1 = (rt[k] >> 8) & 255;
        tokslot[e0 * NTOK + base[e0]] = t;
        base[e0]++;
        tokslot[e1 * NTOK + base[e1]] = t | (1 << 16);
        base[e1]++;
    }
    if (tid == 0) {
        int tot = 0;
        for (int e = 0; e < NEXP; e++) {
            int c = sc[e][1023];
            counts[e] = c;
            int nt = (c + 255) >> 8;
            for (int q = 0; q < nt; q++) tiledesc[tot++] = (e << 8) | q;
        }
        ntiles[0] = tot;
    }
}

// =====================================================================
// 4-buffer ring, BK=32, 256x256-tile GEMM with COUNTED vmcnt (T4).
// LDS: 4 bufs x (A 16KB + B 16KB) = 128 KiB.
// Iter t: stage tile t+3 -> buf[(t+3)&3] (= buf[(t-1)&3], whose readers
// all passed the end-of-(t-1) barrier); 12 ds_read_b128; 32 MFMA;
// vmcnt(8): allows tiles t+2,t+3 (8 loads) outstanding, FORCES tile t+1
// (issued 3 iters (~3700 cyc) earlier) complete. Never vmcnt(0) in
// steady state; tail: vmcnt(4) -> vmcnt(0). ONE barrier per iter.
// Swizzle (64B rows, 4 slots of 16B): slot ^= (row&3)^((row>>2)&3),
// applied on the GLOBAL source (LDS dest linear, involution, rule #21)
// and on the ds_read address. Each wave b128-read touches every bank
// exactly 8x (= 256 words/32 banks, optimal) -> 0 counted conflicts.
// Read-side XOR is lane-constant: f(row)=(rsel&3)^((rsel>>2)&3).
// =====================================================================

#define STAGE4(d, kt)                                        \
    do {                                                     \
        char* dA_ = lds + (d)*32768 + tid * 16;              \
        char* dB_ = dA_ + 16384;                             \
        size_t ko_ = (size_t)(kt)*64;                        \
        gld16(aP[0] + ko_, dA_);                             \
        gld16(aP[1] + ko_, dA_ + 8192);                      \
        gld16(bP[0] + ko_, dB_);                             \
        gld16(bP[1] + ko_, dB_ + 8192);                      \
    } while (0)

#define MMALL()                                                           \
    do {                                                                  \
        _Pragma("unroll") for (int m_ = 0; m_ < 8; m_++)                  \
            _Pragma("unroll") for (int n_ = 0; n_ < 4; n_++)              \
                acc[m_][n_] = MFMA16(af[m_], bfr[n_], acc[m_][n_]);       \
    } while (0)

#define PIPE4(NKT)                                                        \
    f32x4 acc[8][4];                                                      \
    _Pragma("unroll") for (int m_ = 0; m_ < 8; m_++)                      \
        _Pragma("unroll") for (int n_ = 0; n_ < 4; n_++) acc[m_][n_] = (f32x4)0.f; \
    const int aBase = (wr * 128 + rsel) * 64;                             \
    const int bBase = 16384 + (wc * 64 + rsel) * 64;                      \
    const int sOff = ((g4 ^ (rsel & 3) ^ ((rsel >> 2) & 3)) << 4);        \
    STAGE4(0, 0);                                                         \
    STAGE4(1, 1);                                                         \
    STAGE4(2, 2);                                                         \
    WAITVM(8);                                                            \
    S_BARRIER();                                                          \
    for (int t = 0; t < (NKT); ++t) {                                     \
        if (t + 3 < (NKT)) STAGE4((t + 3) & 3, t + 3);                    \
        const char* Tb = lds + (t & 3) * 32768;                           \
        bf16x8 af[8], bfr[4];                                             \
        _Pragma("unroll") for (int m_ = 0; m_ < 8; m_++)                  \
            af[m_] = *(const bf16x8*)(Tb + aBase + m_ * 1024 + sOff);     \
        _Pragma("unroll") for (int n_ = 0; n_ < 4; n_++)                  \
            bfr[n_] = *(const bf16x8*)(Tb + bBase + n_ * 1024 + sOff);    \
        SETPRIO(1); MMALL(); SETPRIO(0);                                  \
        if (t < (NKT)-3) { WAITVM(8); S_BARRIER(); }                      \
        else if (t == (NKT)-3) { WAITVM(4); S_BARRIER(); }                \
        else if (t == (NKT)-2) { WAITVM(0); S_BARRIER(); }                \
    }

// ---------------- gate_up GEMM + swiglu -> h ----------------
// grid (16 col-tiles of 128 h-cols, 72 tile-slots): blockId = bx + 16*by
// -> XCD = bx%8: all blocks sharing a B col-slice land on ONE XCD's L2.
__global__ __launch_bounds__(512, 2) void gateup4p(const u16* __restrict__ xb, const u16* __restrict__ gub,
                                                   const int* __restrict__ counts,
                                                   const int* __restrict__ ntiles, const int* __restrict__ tiledesc,
                                                   const int* __restrict__ tokslot, u16* __restrict__ h) {
    if ((int)blockIdx.y >= ntiles[0]) return;
    int td = tiledesc[blockIdx.y];
    int e = td >> 8;
    int cnt = counts[e];
    int row0 = (td & 255) * 256;
    int c0 = blockIdx.x * 128;

    extern __shared__ char lds[];
    int tid = threadIdx.x;
    int wv = tid >> 6, ln = tid & 63;
    int wr = wv >> 2, wc = wv & 3;
    int rsel = ln & 15, g4 = ln >> 4;

    // staging: thread covers rows srow and 128+srow, dst 16B-slot tid&3
    int srow = tid >> 2, sl = tid & 3;
    int sswz = ((sl ^ (srow & 3) ^ ((srow >> 2) & 3)) << 4);
    const char* aP[2];
    const char* bP[2];
#pragma unroll
    for (int c = 0; c < 2; c++) {
        int r = c * 128 + srow;
        int gr = row0 + r;
        gr = gr < cnt ? gr : cnt - 1;
        int tok = tokslot[e * NTOK + gr] & 0xFFFF;
        aP[c] = (const char*)xb + (size_t)tok * (HID * 2) + sswz;
        // B row r: group r>>6, wi=r&63; wi<32 -> gate col, else up col
        int wi = r & 63;
        int b = (wi >> 5) * 2048 + c0 + (r >> 6) * 32 + (wi & 31);
        bP[c] = (const char*)gub + ((size_t)e * 4096 + b) * (HID * 2) + sswz;
    }

    PIPE4(HID / 32)  // 24 K-tiles

    // epilogue: n in {0,1}=gate, n+2=up; h-col = c0 + wc*32 + n*16 + rsel
#pragma unroll
    for (int mg = 0; mg < 8; mg++) {
#pragma unroll
        for (int j = 0; j < 4; j++) {
            int gr = row0 + wr * 128 + mg * 16 + g4 * 4 + j;
            if (gr >= cnt) continue;
            int ts = tokslot[e * NTOK + gr];
            int tok = ts & 0xFFFF, slot = ts >> 16;
            u16* hrow = h + (size_t)(slot * NTOK + tok) * INTER;
#pragma unroll
            for (int n = 0; n < 2; n++) {
                float gv = acc[mg][n][j];
                float uv = fminf(acc[mg][n + 2][j], 7.0f);
                float sg = gv / (1.0f + __expf(-gv));
                hrow[c0 + wc * 32 + n * 16 + rsel] = f2bf(sg * uv);
            }
        }
    }
}

// ---------------- down GEMM + weighted atomic scatter-add ----------------
// grid (3 col-tiles of 256, 72 tile-slots)
__global__ __launch_bounds__(512, 2) void down4p(const u16* __restrict__ hb, const u16* __restrict__ dnb,
                                                 const int* __restrict__ counts,
                                                 const int* __restrict__ ntiles, const int* __restrict__ tiledesc,
                                                 const int* __restrict__ tokslot,
                                                 const float* __restrict__ wslot, float* __restrict__ out) {
    if ((int)blockIdx.y >= ntiles[0]) return;
    int td = tiledesc[blockIdx.y];
    int e = td >> 8;
    int cnt = counts[e];
    int row0 = (td & 255) * 256;
    int col0 = blockIdx.x * 256;

    extern __shared__ char lds[];
    int tid = threadIdx.x;
    int wv = tid >> 6, ln = tid & 63;
    int wr = wv >> 2, wc = wv & 3;
    int rsel = ln & 15, g4 = ln >> 4;

    int srow = tid >> 2, sl = tid & 3;
    int sswz = ((sl ^ (srow & 3) ^ ((srow >> 2) & 3)) << 4);
    const char* aP[2];
    const char* bP[2];
#pragma unroll
    for (int c = 0; c < 2; c++) {
        int r = c * 128 + srow;
        int gr = row0 + r;
        gr = gr < cnt ? gr : cnt - 1;
        int ts = tokslot[e * NTOK + gr];
        aP[c] = (const char*)hb + (size_t)((ts >> 16) * NTOK + (ts & 0xFFFF)) * (INTER * 2) + sswz;
        bP[c] = (const char*)dnb + ((size_t)e * HID + col0 + r) * (INTER * 2) + sswz;
    }

    PIPE4(INTER / 32)  // 64 K-tiles

#pragma unroll
    for (int mg = 0; mg < 8; mg++) {
#pragma unroll
        for (int j = 0; j < 4; j++) {
            int gr = row0 + wr * 128 + mg * 16 + g4 * 4 + j;
            if (gr >= cnt) continue;
            int ts = tokslot[e * NTOK + gr];
            int tok = ts & 0xFFFF, slot = ts >> 16;
            float w = wslot[slot * NTOK + tok];
#pragma unroll
            for (int n = 0; n < 4; n++) {
                int col = col0 + wc * 64 + n * 16 + rsel;
                atomicAdd(&out[(size_t)tok * HID + col], w * acc[mg][n][j]);
            }
        }
    }
}

// ---------------- launch ----------------
extern "C" void kernel_launch(void* const* d_in, const int* in_sizes, int n_in,
                              void* d_out, int out_size, void* d_ws, size_t ws_size,
                              hipStream_t stream) {
    const float* x = (const float*)d_in[0];
    const float* rw = (const float*)d_in[1];
    const float* gu = (const float*)d_in[2];
    const float* dn = (const float*)d_in[3];
    float* out = (float*)d_out;
    char* ws = (char*)d_ws;

    // workspace layout (bytes)
    int* counts = (int*)(ws + 0);            // 32
    int* ntiles = (int*)(ws + 64);           // 4
    int* tiledesc = (int*)(ws + 128);        // 72*4 -> ends 416
    int* tokslot = (int*)(ws + 512);         // 8*8192*4 -> ends 262656
    float* wslot = (float*)(ws + 262656);    // 2*8192*4 -> ends 328192
    u16* xb = (u16*)(ws + 328192);           // 12,582,912 -> ends 12,911,104
    u16* gub = (u16*)(ws + 12911104);        // 50,331,648 -> ends 63,242,752
    u16* dnb = (u16*)(ws + 63242752);        // 25,165,824 -> ends 88,408,576
    u16* hb = (u16*)(ws + 88408576);         // 67,108,864 -> ends 155,517,440
    // route aliases the head of hb: written by router2, consumed by scatter,
    // then hb is (re)written by gateup4p strictly afterwards on the stream.
    u32* route = (u32*)(ws + 88408576);      // 8192*4

    zero_kernel<<<1024, 256, 0, stream>>>((float4*)out, NTOK * HID / 4);
    cvt_kernel<<<2048, 256, 0, stream>>>(x, xb, NTOK * HID / 8);
    cvt_kernel<<<2048, 256, 0, stream>>>(gu, gub, NEXP * 2 * INTER * HID / 8);
    cvt_kernel<<<2048, 256, 0, stream>>>(dn, dnb, NEXP * HID * INTER / 8);
    router2<<<NTOK / 4, 256, 0, stream>>>(x, rw, route, wslot);
    scatter_kernel<<<1, 1024, 0, stream>>>(route, counts, tokslot, ntiles, tiledesc);
    gateup4p<<<dim3(16, 72), 512, 131072, stream>>>(xb, gub, counts, ntiles, tiledesc, tokslot, hb);
    down4p<<<dim3(3, 72), 512, 131072, stream>>>(hb, dnb, counts, ntiles, tiledesc, tokslot, wslot, out);
}